// Round 5
// baseline (265.148 us; speedup 1.0000x reference)
//
#include <hip/hip_runtime.h>
#include <stdint.h>

#define N_NODES 4096
#define K_NN    40
#define B_CLOUDS 8
#define F_IN    8
#define H_DIM   64
#define O_DIM   128

#define OUT_FEAT_ELEMS (B_CLOUDS * N_NODES * O_DIM)   // 4194304
#define EDGES          (B_CLOUDS * N_NODES * K_NN)    // 1310720

typedef short bf16x8 __attribute__((ext_vector_type(8)));
typedef float f32x4  __attribute__((ext_vector_type(4)));

__device__ __forceinline__ unsigned short f2bf(float f) {
    unsigned u = __float_as_uint(f);
    unsigned r = (u + 0x7FFFu + ((u >> 16) & 1u)) >> 16;   // RNE
    return (unsigned short)r;
}

// wave_shr:1 — lane i receives lane i-1's value, VALU DPP (no DS round-trip).
// Lane 0 gets 0 (bound_ctrl); harmless: lane 0 sentinel always keeps.
__device__ __forceinline__ unsigned shr1_dpp(unsigned v) {
    return (unsigned)__builtin_amdgcn_update_dpp(0, (int)v, 0x138, 0xF, 0xF, true);
}

// One sorted-insert step (proven v3/v5 machinery). mask bits consumed
// ascending, keys (d2<<32|j) ascending across lanes, lane 0 = 0-sentinel.
// Exact for ANY number of inserts (list keeps smallest 63; need top 40).
#define INS_STEP(mask_, dreg_, Rhi_, Rlo_)                                         \
    {                                                                              \
        const int src = (int)__builtin_ctzll(mask_);                               \
        mask_ &= mask_ - 1;                                                        \
        const unsigned long long kb =                                              \
            ((unsigned long long)(unsigned)__builtin_amdgcn_readlane((int)(dreg_), src) << 32) \
            | (unsigned)((c << 6) | src);                                          \
        const unsigned long long RP = ((unsigned long long)Rhi_ << 32) | Rlo_;     \
        const bool keep = (RP <= kb);                                              \
        const unsigned uplo = shr1_dpp(Rlo_);                                      \
        const unsigned uphi = shr1_dpp(Rhi_);                                      \
        const unsigned long long up = ((unsigned long long)uphi << 32) | uplo;     \
        const unsigned long long mx = (up > kb) ? up : kb;                         \
        const unsigned long long nw = keep ? RP : mx;                              \
        Rhi_ = (unsigned)(nw >> 32);                                               \
        Rlo_ = (unsigned)nw;                                                       \
    }

// ---------------------------------------------------------------------------
// Kernel A: exact KNN v8 — 2 targets/wave (iA even, iB=iA+1), NO dsave
// (recompute in pass 2; bitwise-identical fp ops), fixed 18-bit radix
// threshold (rank 41; self d2=0 rides through pass 1 / radix, masked from
// pass-2 ballot at its single chunk). Serial insert only sees ~46 true
// qualifiers per target; A/B chains interleave for ILP; 64 KB LDS ->
// 2 blocks/CU -> 8 waves/SIMD for TLP. Exact for any qualifier count.
// ---------------------------------------------------------------------------
__global__ __launch_bounds__(1024, 8) void knn_kernel(const float* __restrict__ pos,
                                                      float* __restrict__ out)
{
    __shared__ float4 ppos[N_NODES];   // 64 KB; 2 blocks/CU

    const int b  = blockIdx.x >> 7;           // 128 blocks per cloud
    const int i0 = (blockIdx.x & 127) << 5;   // 32 targets per block
    const float* posb = pos + (size_t)b * N_NODES * 3;

    for (int n = threadIdx.x; n < N_NODES; n += 1024) {
        ppos[n] = make_float4(posb[3 * n], posb[3 * n + 1], posb[3 * n + 2], 0.f);
    }
    __syncthreads();

    const int wave = threadIdx.x >> 6;
    const int lane = threadIdx.x & 63;
    const int iA = i0 + (wave << 1);
    const int iB = iA + 1;                    // same 64-chunk as iA
    const int ci = iA >> 6;                   // chunk containing both selves
    const int liA = iA & 63;
    const int liB = iB & 63;

    const float4 pa4 = ppos[iA];
    const float4 pb4 = ppos[iB];
    const float pax = pa4.x, pay = pa4.y, paz = pa4.z;
    const float pbx = pb4.x, pby = pb4.y, pbz = pb4.z;

    // ---- pass 1: distances (self included, d2=0); 4x top-1 per target ----
    unsigned mA[4] = {~0u, ~0u, ~0u, ~0u};
    unsigned mB[4] = {~0u, ~0u, ~0u, ~0u};
#pragma unroll
    for (int c = 0; c < 64; ++c) {
        const float4 p = ppos[(c << 6) | lane];
        // bitwise-exact fp32: ((dx*dx + dy*dy) + dz*dz), no FMA contraction
        const float dxA = __fsub_rn(pax, p.x);
        const float dyA = __fsub_rn(pay, p.y);
        const float dzA = __fsub_rn(paz, p.z);
        const float d2A = __fadd_rn(__fadd_rn(__fmul_rn(dxA, dxA), __fmul_rn(dyA, dyA)),
                                    __fmul_rn(dzA, dzA));
        const float dxB = __fsub_rn(pbx, p.x);
        const float dyB = __fsub_rn(pby, p.y);
        const float dzB = __fsub_rn(pbz, p.z);
        const float d2B = __fadd_rn(__fadd_rn(__fmul_rn(dxB, dxB), __fmul_rn(dyB, dyB)),
                                    __fmul_rn(dzB, dzB));
        mA[c & 3] = min(mA[c & 3], __float_as_uint(d2A));
        mB[c & 3] = min(mB[c & 3], __float_as_uint(d2B));
    }

    // ---- truncated radix-select (interleaved A/B): t >= 40th real dist ----
    // kept set = 256 per-(lane,class) mins incl. one artificial 0 (self);
    // rank-41 of kept >= rank-40 of real; 18 bits + round-up => superset
    // threshold unconditionally (proven v7 logic).
    unsigned accA = 0, accB = 0;
    for (int bit = 30; bit >= 13; --bit) {
        const unsigned tA = accA | (1u << bit);
        const unsigned tB = accB | (1u << bit);
        const int cA = __popcll(__ballot(mA[0] < tA)) + __popcll(__ballot(mA[1] < tA))
                     + __popcll(__ballot(mA[2] < tA)) + __popcll(__ballot(mA[3] < tA));
        const int cB = __popcll(__ballot(mB[0] < tB)) + __popcll(__ballot(mB[1] < tB))
                     + __popcll(__ballot(mB[2] < tB)) + __popcll(__ballot(mB[3] < tB));
        if (cA <= K_NN) accA = tA;
        if (cB <= K_NN) accB = tB;
    }
    const unsigned thA = accA | 0x1FFFu;
    const unsigned thB = accB | 0x1FFFu;

    // ---- pass 2: recompute + fixed-threshold serial insert (A/B chains) ----
    unsigned RAhi = (lane == 0) ? 0u : 0xFFFFFFFFu;
    unsigned RAlo = (lane == 0) ? 0u : 0xFFFFFFFFu;
    unsigned RBhi = RAhi, RBlo = RAlo;

#pragma unroll 4
    for (int c = 0; c < 64; ++c) {
        const float4 p = ppos[(c << 6) | lane];
        const float dxA = __fsub_rn(pax, p.x);
        const float dyA = __fsub_rn(pay, p.y);
        const float dzA = __fsub_rn(paz, p.z);
        const float d2A = __fadd_rn(__fadd_rn(__fmul_rn(dxA, dxA), __fmul_rn(dyA, dyA)),
                                    __fmul_rn(dzA, dzA));
        const float dxB = __fsub_rn(pbx, p.x);
        const float dyB = __fsub_rn(pby, p.y);
        const float dzB = __fsub_rn(pbz, p.z);
        const float d2B = __fadd_rn(__fadd_rn(__fmul_rn(dxB, dxB), __fmul_rn(dyB, dyB)),
                                    __fmul_rn(dzB, dzB));
        const unsigned dA = __float_as_uint(d2A);
        const unsigned dB = __float_as_uint(d2B);

        unsigned long long maskA = __ballot(dA <= thA);
        unsigned long long maskB = __ballot(dB <= thB);
        if (c == ci) {                         // wave-uniform: drop selves
            maskA &= ~(1ull << liA);
            maskB &= ~(1ull << liB);
        }

        while (maskA && maskB) {               // two independent chains
            INS_STEP(maskA, dA, RAhi, RAlo);
            INS_STEP(maskB, dB, RBhi, RBlo);
        }
        while (maskA) INS_STEP(maskA, dA, RAhi, RAlo);
        while (maskB) INS_STEP(maskB, dB, RBhi, RBlo);
    }

    // Emit edges from lanes 1..40: src = global neighbor id, tgt = target id
    float* src_out = out + OUT_FEAT_ELEMS;
    float* tgt_out = src_out + EDGES;
    const int giA = b * N_NODES + iA;
    const int giB = giA + 1;
    const unsigned el = (unsigned)(lane - 1);
    if (el < K_NN) {
        src_out[(size_t)giA * K_NN + el] = (float)(b * N_NODES + (int)RAlo);
        tgt_out[(size_t)giA * K_NN + el] = (float)giA;
        src_out[(size_t)giB * K_NN + el] = (float)(b * N_NODES + (int)RBlo);
        tgt_out[(size_t)giB * K_NN + el] = (float)giB;
    }
}

// ---------------------------------------------------------------------------
// Kernel P: precompute W2 and W1 bf16 B-fragments into d_ws — R14, proven.
// ---------------------------------------------------------------------------
__global__ __launch_bounds__(256) void prep_kernel(const float* __restrict__ W2,
                                                   const float* __restrict__ W1,
                                                   unsigned short* __restrict__ ws)
{
    const int idx = blockIdx.x * 256 + threadIdx.x;   // 0..10239
    if (idx < 8192) {
        const int j    = idx & 7;
        const int lane = (idx >> 3) & 63;
        const int kt   = (idx >> 9) & 1;
        const int nt   = idx >> 10;
        const int k = kt * 32 + (lane >> 4) * 8 + j;
        const int n = nt * 16 + (lane & 15);
        ws[idx] = f2bf(W2[k * O_DIM + n]);
    } else if (idx < 8192 + 2048) {
        const int t = idx - 8192;
        const int j    = t & 7;
        const int lane = (t >> 3) & 63;
        const int nt   = t >> 9;          // 0..3
        const int k = (lane >> 4) * 8 + j;          // 0..31
        const int n = nt * 16 + (lane & 15);        // hidden channel
        ws[idx] = (k < 11) ? f2bf(W1[k * H_DIM + n]) : (unsigned short)0;
    }
}

// ---------------------------------------------------------------------------
// Kernel B: per-edge MLP, both layers MFMA — UNCHANGED from R14 (proven).
// ---------------------------------------------------------------------------
#define HSTR 72   // Hh row stride (bf16): 144 B
#define KSTR 40   // msg row stride (bf16): 80 B, 16B-aligned rows

__global__ __launch_bounds__(256, 4) void conv_kernel(
    const float* __restrict__ x, const float* __restrict__ pos,
    const unsigned short* __restrict__ w2f,   // d_ws: w2 frags [0,8192)
    const unsigned short* __restrict__ w1f,   // d_ws: w1 frags [8192,10240)
    const float* __restrict__ b1, const float* __restrict__ b2,
    float* __restrict__ out)
{
    __shared__ __align__(16) unsigned short Hh[4][48 * HSTR];    // 27648 B

    const int b    = blockIdx.x >> 10;
    const int i0   = (blockIdx.x & 1023) << 2;
    const int wave = threadIdx.x >> 6;
    const int lane = threadIdx.x & 63;
    const int quad = lane >> 4;
    const int col  = lane & 15;
    const int i    = i0 + wave;
    const int gi   = b * N_NODES + i;

    unsigned short* Hw = Hh[wave];

    // ---- phase 1: lane n (<48) gathers message row n, stages bf16 to LDS ----
    const float* src_edges = out + OUT_FEAT_ELEMS;
    if (lane < 48) {
        int j;
        if (lane < K_NN) j = (int)src_edges[(size_t)gi * K_NN + lane] - b * N_NODES;
        else             j = i;   // rows 40..47: self row + pad dups (max-safe)
        const float* xr = x + ((size_t)b * N_NODES + j) * F_IN;
        float4 xa = *(const float4*)xr;
        float4 xb = *(const float4*)(xr + 4);
        const float* pj = pos + ((size_t)b * N_NODES + j) * 3;
        const float* pi = pos + ((size_t)b * N_NODES + i) * 3;
        unsigned w[16];
#pragma unroll
        for (int t = 0; t < 16; ++t) w[t] = 0;
        w[0] = (unsigned)f2bf(xa.x) | ((unsigned)f2bf(xa.y) << 16);
        w[1] = (unsigned)f2bf(xa.z) | ((unsigned)f2bf(xa.w) << 16);
        w[2] = (unsigned)f2bf(xb.x) | ((unsigned)f2bf(xb.y) << 16);
        w[3] = (unsigned)f2bf(xb.z) | ((unsigned)f2bf(xb.w) << 16);
        w[4] = (unsigned)f2bf(pj[0] - pi[0]) | ((unsigned)f2bf(pj[1] - pi[1]) << 16);
        w[5] = (unsigned)f2bf(pj[2] - pi[2]);
        unsigned* mrow = (unsigned*)(Hw + lane * KSTR);
        *(uint4*)(mrow)      = make_uint4(w[0], w[1], w[2], w[3]);
        *(uint4*)(mrow + 4)  = make_uint4(w[4], w[5], w[6], w[7]);
        *(uint4*)(mrow + 8)  = make_uint4(w[8], w[9], w[10], w[11]);
        *(uint4*)(mrow + 12) = make_uint4(w[12], w[13], w[14], w[15]);
    }
    // same-wave ds_write -> ds_read: ordered by lgkmcnt, no barrier needed

    // ---- layer 1 via MFMA: H[48x64] = msg[48x32] . W1[32x64] ----
    bf16x8 Am[3];
#pragma unroll
    for (int mt = 0; mt < 3; ++mt)
        Am[mt] = *(const bf16x8*)&Hw[(mt * 16 + col) * KSTR + quad * 8];

    const bf16x8* W1f = (const bf16x8*)w1f;
    float hreg[12][4];
#pragma unroll
    for (int nt = 0; nt < 4; ++nt) {
        bf16x8 Bn = W1f[nt * 64 + lane];
        const float bias = b1[nt * 16 + col];
        f32x4 d0 = {bias, bias, bias, bias};
        f32x4 d1 = d0, d2 = d0;
        d0 = __builtin_amdgcn_mfma_f32_16x16x32_bf16(Am[0], Bn, d0, 0, 0, 0);
        d1 = __builtin_amdgcn_mfma_f32_16x16x32_bf16(Am[1], Bn, d1, 0, 0, 0);
        d2 = __builtin_amdgcn_mfma_f32_16x16x32_bf16(Am[2], Bn, d2, 0, 0, 0);
#pragma unroll
        for (int r = 0; r < 4; ++r) {
            hreg[nt * 3 + 0][r] = fmaxf(d0[r], 0.0f);
            hreg[nt * 3 + 1][r] = fmaxf(d1[r], 0.0f);
            hreg[nt * 3 + 2][r] = fmaxf(d2[r], 0.0f);
        }
    }

    // msg fully consumed -> overwrite region as Hh[row][hidden]
#pragma unroll
    for (int nt = 0; nt < 4; ++nt)
#pragma unroll
        for (int mt = 0; mt < 3; ++mt)
#pragma unroll
            for (int r = 0; r < 4; ++r)
                Hw[(mt * 16 + quad * 4 + r) * HSTR + nt * 16 + col] =
                    f2bf(hreg[nt * 3 + mt][r]);

    // ---- layer 2 via MFMA ----
    bf16x8 Af[3][2];
#pragma unroll
    for (int mt = 0; mt < 3; ++mt)
#pragma unroll
        for (int kt = 0; kt < 2; ++kt)
            Af[mt][kt] = *(const bf16x8*)&Hw[(mt * 16 + col) * HSTR + kt * 32 + quad * 8];

    const bf16x8* Bws = (const bf16x8*)w2f;
#pragma unroll
    for (int nt = 0; nt < 8; ++nt) {
        bf16x8 B0 = Bws[nt * 128 + lane];
        bf16x8 B1 = Bws[nt * 128 + 64 + lane];

        f32x4 c0 = {0.f, 0.f, 0.f, 0.f};
        f32x4 c1 = {0.f, 0.f, 0.f, 0.f};
        f32x4 c2 = {0.f, 0.f, 0.f, 0.f};
        c0 = __builtin_amdgcn_mfma_f32_16x16x32_bf16(Af[0][0], B0, c0, 0, 0, 0);
        c1 = __builtin_amdgcn_mfma_f32_16x16x32_bf16(Af[1][0], B0, c1, 0, 0, 0);
        c2 = __builtin_amdgcn_mfma_f32_16x16x32_bf16(Af[2][0], B0, c2, 0, 0, 0);
        c0 = __builtin_amdgcn_mfma_f32_16x16x32_bf16(Af[0][1], B1, c0, 0, 0, 0);
        c1 = __builtin_amdgcn_mfma_f32_16x16x32_bf16(Af[1][1], B1, c1, 0, 0, 0);
        c2 = __builtin_amdgcn_mfma_f32_16x16x32_bf16(Af[2][1], B1, c2, 0, 0, 0);

        float vm = c0[0];
        vm = fmaxf(vm, c0[1]); vm = fmaxf(vm, c0[2]); vm = fmaxf(vm, c0[3]);
        vm = fmaxf(vm, c1[0]); vm = fmaxf(vm, c1[1]); vm = fmaxf(vm, c1[2]); vm = fmaxf(vm, c1[3]);
        vm = fmaxf(vm, c2[0]); vm = fmaxf(vm, c2[1]); vm = fmaxf(vm, c2[2]); vm = fmaxf(vm, c2[3]);
        vm = fmaxf(vm, __shfl_xor(vm, 16));
        vm = fmaxf(vm, __shfl_xor(vm, 32));
        vm += b2[nt * 16 + col];

        if (lane < 16) out[(size_t)gi * O_DIM + nt * 16 + lane] = vm;
    }
}

// ---------------------------------------------------------------------------
extern "C" void kernel_launch(void* const* d_in, const int* in_sizes, int n_in,
                              void* d_out, int out_size, void* d_ws, size_t ws_size,
                              hipStream_t stream) {
    const float* x   = (const float*)d_in[0];
    const float* pos = (const float*)d_in[1];
    const float* W1  = (const float*)d_in[2];
    const float* b1  = (const float*)d_in[3];
    const float* W2  = (const float*)d_in[4];
    const float* b2  = (const float*)d_in[5];
    float* out = (float*)d_out;
    unsigned short* ws = (unsigned short*)d_ws;   // 10240 bf16 = 20.5 KB

    prep_kernel<<<40, 256, 0, stream>>>(W2, W1, ws);
    knn_kernel<<<(B_CLOUDS * N_NODES) / 32, 1024, 0, stream>>>(pos, out);
    conv_kernel<<<(B_CLOUDS * N_NODES) / 4, 256, 0, stream>>>(
        x, pos, ws, ws + 8192, b1, b2, out);
}

// Round 6
// 214.319 us; speedup vs baseline: 1.2372x; 1.2372x over previous
//
#include <hip/hip_runtime.h>
#include <stdint.h>

#define N_NODES 4096
#define K_NN    40
#define B_CLOUDS 8
#define F_IN    8
#define H_DIM   64
#define O_DIM   128

#define OUT_FEAT_ELEMS (B_CLOUDS * N_NODES * O_DIM)   // 4194304
#define EDGES          (B_CLOUDS * N_NODES * K_NN)    // 1310720

typedef short bf16x8 __attribute__((ext_vector_type(8)));
typedef float f32x4  __attribute__((ext_vector_type(4)));

__device__ __forceinline__ unsigned short f2bf(float f) {
    unsigned u = __float_as_uint(f);
    unsigned r = (u + 0x7FFFu + ((u >> 16) & 1u)) >> 16;   // RNE
    return (unsigned short)r;
}

// wave_shr:1 — lane i receives lane i-1's value (COLD fallback path only).
__device__ __forceinline__ unsigned shr1_dpp(unsigned v) {
    return (unsigned)__builtin_amdgcn_update_dpp(0, (int)v, 0x138, 0xF, 0xF, true);
}

// One sorted-insert step (proven v3/v5 machinery) — COLD fallback only.
#define INS_STEP(mask_, dreg_, Rhi_, Rlo_)                                         \
    {                                                                              \
        const int src = (int)__builtin_ctzll(mask_);                               \
        mask_ &= mask_ - 1;                                                        \
        const unsigned long long kb =                                              \
            ((unsigned long long)(unsigned)__builtin_amdgcn_readlane((int)(dreg_), src) << 32) \
            | (unsigned)((c << 6) | src);                                          \
        const unsigned long long RP = ((unsigned long long)Rhi_ << 32) | Rlo_;     \
        const bool keep = (RP <= kb);                                              \
        const unsigned uplo = shr1_dpp(Rlo_);                                      \
        const unsigned uphi = shr1_dpp(Rhi_);                                      \
        const unsigned long long up = ((unsigned long long)uphi << 32) | uplo;     \
        const unsigned long long mx = (up > kb) ? up : kb;                         \
        const unsigned long long nw = keep ? RP : mx;                              \
        Rhi_ = (unsigned)(nw >> 32);                                               \
        Rlo_ = (unsigned)nw;                                                       \
    }

// ---------------------------------------------------------------------------
// Kernel A: exact KNN v9 — branch-free hot path, NO dsave (recompute).
//   P1: dist + 4x top-1 mins (no branches, ~30 live VGPRs).
//   RS: 18-bit truncated radix, rank 41 (self d2=0 rides along) — R4-proven.
//   P2: recompute dist + branch-free ballot/mbcnt compaction into 8 KB LDS.
//   Sort: 64-lane bitonic on u64 keys (R4-proven), emit skipping self.
//   Overflow >64 qualifiers (P~3e-6): COLD exact serial-insert fallback.
// Theory: v5's cost was the ~46-iter data-dependent while loop (branch +
// refetch + serial chain, invisible to VALUBusy). R4 proved the branch-free
// replacement but spilled via dsave[64]; v9 recomputes instead.
// ---------------------------------------------------------------------------
__global__ __launch_bounds__(1024, 8) void knn_kernel(const float* __restrict__ pos,
                                                      float* __restrict__ out)
{
    __shared__ float4 ppos[N_NODES];                 // 64 KB
    __shared__ unsigned long long qual[16][64];      // 8 KB -> 72 KB total

    const int b  = blockIdx.x >> 8;           // 256 blocks per cloud
    const int i0 = (blockIdx.x & 255) << 4;   // 16 targets per block
    const float* posb = pos + (size_t)b * N_NODES * 3;

    for (int n = threadIdx.x; n < N_NODES; n += 1024) {
        ppos[n] = make_float4(posb[3 * n], posb[3 * n + 1], posb[3 * n + 2], 0.f);
    }
    __syncthreads();

    const int wave = threadIdx.x >> 6;
    const int lane = threadIdx.x & 63;
    const int i = i0 + wave;

    const float4 pi4 = ppos[i];
    const float pix = pi4.x, piy = pi4.y, piz = pi4.z;

    // ---- pass 1: distances (self included, d2=0); 4x top-1 mins ----
    unsigned m0 = ~0u, m1 = ~0u, m2 = ~0u, m3 = ~0u;
#pragma unroll 8
    for (int c = 0; c < 64; ++c) {
        const float4 p = ppos[(c << 6) | lane];
        // bitwise-exact fp32: ((dx*dx + dy*dy) + dz*dz), no FMA contraction
        const float dx = __fsub_rn(pix, p.x);
        const float dy = __fsub_rn(piy, p.y);
        const float dz = __fsub_rn(piz, p.z);
        const float d2 = __fadd_rn(__fadd_rn(__fmul_rn(dx, dx), __fmul_rn(dy, dy)),
                                   __fmul_rn(dz, dz));
        const unsigned d2b = __float_as_uint(d2);
        if ((c & 3) == 0)      m0 = min(m0, d2b);
        else if ((c & 3) == 1) m1 = min(m1, d2b);
        else if ((c & 3) == 2) m2 = min(m2, d2b);
        else                   m3 = min(m3, d2b);
    }

    // ---- truncated radix-select: t >= 40th-smallest REAL distance ----
    // kept = 256 per-(lane,class) mins incl. one artificial 0 (self); rank-41
    // of kept >= rank-40 of real; 18 bits + round-up => superset threshold
    // unconditionally (R4-proven logic).
    unsigned acc = 0;
    for (int bit = 30; bit >= 13; --bit) {
        const unsigned test = acc | (1u << bit);
        const int cnt = __popcll(__ballot(m0 < test)) + __popcll(__ballot(m1 < test))
                      + __popcll(__ballot(m2 < test)) + __popcll(__ballot(m3 < test));
        if (cnt <= K_NN) acc = test;
    }
    const unsigned t = acc | 0x1FFFu;

    // ---- pass 2: recompute + branch-free compaction into qual[wave] ----
    unsigned long long* qw = qual[wave];
    int base = 0;
#pragma unroll 4
    for (int c = 0; c < 64; ++c) {
        const float4 p = ppos[(c << 6) | lane];
        const float dx = __fsub_rn(pix, p.x);
        const float dy = __fsub_rn(piy, p.y);
        const float dz = __fsub_rn(piz, p.z);
        const float d2 = __fadd_rn(__fadd_rn(__fmul_rn(dx, dx), __fmul_rn(dy, dy)),
                                   __fmul_rn(dz, dz));
        const unsigned d2b = __float_as_uint(d2);
        const bool q = d2b <= t;
        const unsigned long long mk = __ballot(q);
        const unsigned mb = __builtin_amdgcn_mbcnt_hi(
            (unsigned)(mk >> 32), __builtin_amdgcn_mbcnt_lo((unsigned)mk, 0u));
        const int idx = base + (int)mb;
        if (q && idx < 64)    // predicated store; clamp protects neighbors
            qw[idx] = ((unsigned long long)d2b << 32) | (unsigned)((c << 6) | lane);
        base += (int)__popcll(mk);
    }

    float* src_out = out + OUT_FEAT_ELEMS;
    float* tgt_out = src_out + EDGES;
    const int gi = b * N_NODES + i;

    if (base <= 64) {
        // ---- bitonic sort of 64 u64 keys across lanes (21 parallel CEs) ----
        unsigned long long key = (lane < base) ? qw[lane] : ~0ull;
#pragma unroll
        for (int k = 2; k <= 64; k <<= 1) {
#pragma unroll
            for (int j = k >> 1; j > 0; j >>= 1) {
                const unsigned long long p = __shfl_xor(key, j, 64);
                const bool up = (lane & k) == 0;
                const bool takeMin = (((lane & j) == 0) == up);
                const bool less = key < p;
                const unsigned long long mn = less ? key : p;
                const unsigned long long mx = less ? p : key;
                key = takeMin ? mn : mx;
            }
        }
        // locate self (key low word == i; self d2=0 always qualifies), emit 40
        const unsigned lo = (unsigned)key;
        const unsigned long long sm = __ballot(lo == (unsigned)i);
        const int ps = (int)__builtin_ctzll(sm);
        const int el = lane - (lane > ps ? 1 : 0);
        if (lane != ps && el < K_NN) {
            src_out[(size_t)gi * K_NN + el] = (float)(b * N_NODES + (int)lo);
            tgt_out[(size_t)gi * K_NN + el] = (float)gi;
        }
    } else {
        // ---- COLD exact fallback: proven serial insert, recompute dist ----
        const int ci = i >> 6;
        const int li = i & 63;
        unsigned Rhi = (lane == 0) ? 0u : 0xFFFFFFFFu;
        unsigned Rlo = (lane == 0) ? 0u : 0xFFFFFFFFu;
        for (int c = 0; c < 64; ++c) {
            const float4 p = ppos[(c << 6) | lane];
            const float dx = __fsub_rn(pix, p.x);
            const float dy = __fsub_rn(piy, p.y);
            const float dz = __fsub_rn(piz, p.z);
            const float d2 = __fadd_rn(__fadd_rn(__fmul_rn(dx, dx), __fmul_rn(dy, dy)),
                                       __fmul_rn(dz, dz));
            const unsigned d2b = __float_as_uint(d2);
            unsigned long long mask = __ballot(d2b <= t);
            if (c == ci) mask &= ~(1ull << li);   // exclude self
            while (mask) INS_STEP(mask, d2b, Rhi, Rlo);
        }
        const unsigned el = (unsigned)(lane - 1);
        if (el < K_NN) {
            src_out[(size_t)gi * K_NN + el] = (float)(b * N_NODES + (int)Rlo);
            tgt_out[(size_t)gi * K_NN + el] = (float)gi;
        }
    }
}

// ---------------------------------------------------------------------------
// Kernel P: precompute W2 and W1 bf16 B-fragments into d_ws — R14, proven.
// ---------------------------------------------------------------------------
__global__ __launch_bounds__(256) void prep_kernel(const float* __restrict__ W2,
                                                   const float* __restrict__ W1,
                                                   unsigned short* __restrict__ ws)
{
    const int idx = blockIdx.x * 256 + threadIdx.x;   // 0..10239
    if (idx < 8192) {
        const int j    = idx & 7;
        const int lane = (idx >> 3) & 63;
        const int kt   = (idx >> 9) & 1;
        const int nt   = idx >> 10;
        const int k = kt * 32 + (lane >> 4) * 8 + j;
        const int n = nt * 16 + (lane & 15);
        ws[idx] = f2bf(W2[k * O_DIM + n]);
    } else if (idx < 8192 + 2048) {
        const int t = idx - 8192;
        const int j    = t & 7;
        const int lane = (t >> 3) & 63;
        const int nt   = t >> 9;          // 0..3
        const int k = (lane >> 4) * 8 + j;          // 0..31
        const int n = nt * 16 + (lane & 15);        // hidden channel
        ws[idx] = (k < 11) ? f2bf(W1[k * H_DIM + n]) : (unsigned short)0;
    }
}

// ---------------------------------------------------------------------------
// Kernel B: per-edge MLP, both layers MFMA — UNCHANGED from R14 (proven).
// ---------------------------------------------------------------------------
#define HSTR 72   // Hh row stride (bf16): 144 B
#define KSTR 40   // msg row stride (bf16): 80 B, 16B-aligned rows

__global__ __launch_bounds__(256, 4) void conv_kernel(
    const float* __restrict__ x, const float* __restrict__ pos,
    const unsigned short* __restrict__ w2f,   // d_ws: w2 frags [0,8192)
    const unsigned short* __restrict__ w1f,   // d_ws: w1 frags [8192,10240)
    const float* __restrict__ b1, const float* __restrict__ b2,
    float* __restrict__ out)
{
    __shared__ __align__(16) unsigned short Hh[4][48 * HSTR];    // 27648 B

    const int b    = blockIdx.x >> 10;
    const int i0   = (blockIdx.x & 1023) << 2;
    const int wave = threadIdx.x >> 6;
    const int lane = threadIdx.x & 63;
    const int quad = lane >> 4;
    const int col  = lane & 15;
    const int i    = i0 + wave;
    const int gi   = b * N_NODES + i;

    unsigned short* Hw = Hh[wave];

    // ---- phase 1: lane n (<48) gathers message row n, stages bf16 to LDS ----
    const float* src_edges = out + OUT_FEAT_ELEMS;
    if (lane < 48) {
        int j;
        if (lane < K_NN) j = (int)src_edges[(size_t)gi * K_NN + lane] - b * N_NODES;
        else             j = i;   // rows 40..47: self row + pad dups (max-safe)
        const float* xr = x + ((size_t)b * N_NODES + j) * F_IN;
        float4 xa = *(const float4*)xr;
        float4 xb = *(const float4*)(xr + 4);
        const float* pj = pos + ((size_t)b * N_NODES + j) * 3;
        const float* pi = pos + ((size_t)b * N_NODES + i) * 3;
        unsigned w[16];
#pragma unroll
        for (int t = 0; t < 16; ++t) w[t] = 0;
        w[0] = (unsigned)f2bf(xa.x) | ((unsigned)f2bf(xa.y) << 16);
        w[1] = (unsigned)f2bf(xa.z) | ((unsigned)f2bf(xa.w) << 16);
        w[2] = (unsigned)f2bf(xb.x) | ((unsigned)f2bf(xb.y) << 16);
        w[3] = (unsigned)f2bf(xb.z) | ((unsigned)f2bf(xb.w) << 16);
        w[4] = (unsigned)f2bf(pj[0] - pi[0]) | ((unsigned)f2bf(pj[1] - pi[1]) << 16);
        w[5] = (unsigned)f2bf(pj[2] - pi[2]);
        unsigned* mrow = (unsigned*)(Hw + lane * KSTR);
        *(uint4*)(mrow)      = make_uint4(w[0], w[1], w[2], w[3]);
        *(uint4*)(mrow + 4)  = make_uint4(w[4], w[5], w[6], w[7]);
        *(uint4*)(mrow + 8)  = make_uint4(w[8], w[9], w[10], w[11]);
        *(uint4*)(mrow + 12) = make_uint4(w[12], w[13], w[14], w[15]);
    }
    // same-wave ds_write -> ds_read: ordered by lgkmcnt, no barrier needed

    // ---- layer 1 via MFMA: H[48x64] = msg[48x32] . W1[32x64] ----
    bf16x8 Am[3];
#pragma unroll
    for (int mt = 0; mt < 3; ++mt)
        Am[mt] = *(const bf16x8*)&Hw[(mt * 16 + col) * KSTR + quad * 8];

    const bf16x8* W1f = (const bf16x8*)w1f;
    float hreg[12][4];
#pragma unroll
    for (int nt = 0; nt < 4; ++nt) {
        bf16x8 Bn = W1f[nt * 64 + lane];
        const float bias = b1[nt * 16 + col];
        f32x4 d0 = {bias, bias, bias, bias};
        f32x4 d1 = d0, d2 = d0;
        d0 = __builtin_amdgcn_mfma_f32_16x16x32_bf16(Am[0], Bn, d0, 0, 0, 0);
        d1 = __builtin_amdgcn_mfma_f32_16x16x32_bf16(Am[1], Bn, d1, 0, 0, 0);
        d2 = __builtin_amdgcn_mfma_f32_16x16x32_bf16(Am[2], Bn, d2, 0, 0, 0);
#pragma unroll
        for (int r = 0; r < 4; ++r) {
            hreg[nt * 3 + 0][r] = fmaxf(d0[r], 0.0f);
            hreg[nt * 3 + 1][r] = fmaxf(d1[r], 0.0f);
            hreg[nt * 3 + 2][r] = fmaxf(d2[r], 0.0f);
        }
    }

    // msg fully consumed -> overwrite region as Hh[row][hidden]
#pragma unroll
    for (int nt = 0; nt < 4; ++nt)
#pragma unroll
        for (int mt = 0; mt < 3; ++mt)
#pragma unroll
            for (int r = 0; r < 4; ++r)
                Hw[(mt * 16 + quad * 4 + r) * HSTR + nt * 16 + col] =
                    f2bf(hreg[nt * 3 + mt][r]);

    // ---- layer 2 via MFMA ----
    bf16x8 Af[3][2];
#pragma unroll
    for (int mt = 0; mt < 3; ++mt)
#pragma unroll
        for (int kt = 0; kt < 2; ++kt)
            Af[mt][kt] = *(const bf16x8*)&Hw[(mt * 16 + col) * HSTR + kt * 32 + quad * 8];

    const bf16x8* Bws = (const bf16x8*)w2f;
#pragma unroll
    for (int nt = 0; nt < 8; ++nt) {
        bf16x8 B0 = Bws[nt * 128 + lane];
        bf16x8 B1 = Bws[nt * 128 + 64 + lane];

        f32x4 c0 = {0.f, 0.f, 0.f, 0.f};
        f32x4 c1 = {0.f, 0.f, 0.f, 0.f};
        f32x4 c2 = {0.f, 0.f, 0.f, 0.f};
        c0 = __builtin_amdgcn_mfma_f32_16x16x32_bf16(Af[0][0], B0, c0, 0, 0, 0);
        c1 = __builtin_amdgcn_mfma_f32_16x16x32_bf16(Af[1][0], B0, c1, 0, 0, 0);
        c2 = __builtin_amdgcn_mfma_f32_16x16x32_bf16(Af[2][0], B0, c2, 0, 0, 0);
        c0 = __builtin_amdgcn_mfma_f32_16x16x32_bf16(Af[0][1], B1, c0, 0, 0, 0);
        c1 = __builtin_amdgcn_mfma_f32_16x16x32_bf16(Af[1][1], B1, c1, 0, 0, 0);
        c2 = __builtin_amdgcn_mfma_f32_16x16x32_bf16(Af[2][1], B1, c2, 0, 0, 0);

        float vm = c0[0];
        vm = fmaxf(vm, c0[1]); vm = fmaxf(vm, c0[2]); vm = fmaxf(vm, c0[3]);
        vm = fmaxf(vm, c1[0]); vm = fmaxf(vm, c1[1]); vm = fmaxf(vm, c1[2]); vm = fmaxf(vm, c1[3]);
        vm = fmaxf(vm, c2[0]); vm = fmaxf(vm, c2[1]); vm = fmaxf(vm, c2[2]); vm = fmaxf(vm, c2[3]);
        vm = fmaxf(vm, __shfl_xor(vm, 16));
        vm = fmaxf(vm, __shfl_xor(vm, 32));
        vm += b2[nt * 16 + col];

        if (lane < 16) out[(size_t)gi * O_DIM + nt * 16 + lane] = vm;
    }
}

// ---------------------------------------------------------------------------
extern "C" void kernel_launch(void* const* d_in, const int* in_sizes, int n_in,
                              void* d_out, int out_size, void* d_ws, size_t ws_size,
                              hipStream_t stream) {
    const float* x   = (const float*)d_in[0];
    const float* pos = (const float*)d_in[1];
    const float* W1  = (const float*)d_in[2];
    const float* b1  = (const float*)d_in[3];
    const float* W2  = (const float*)d_in[4];
    const float* b2  = (const float*)d_in[5];
    float* out = (float*)d_out;
    unsigned short* ws = (unsigned short*)d_ws;   // 10240 bf16 = 20.5 KB

    prep_kernel<<<40, 256, 0, stream>>>(W2, W1, ws);
    knn_kernel<<<(B_CLOUDS * N_NODES) / 16, 1024, 0, stream>>>(pos, out);
    conv_kernel<<<(B_CLOUDS * N_NODES) / 4, 256, 0, stream>>>(
        x, pos, ws, ws + 8192, b1, b2, out);
}

// Round 7
// 196.398 us; speedup vs baseline: 1.3501x; 1.0912x over previous
//
#include <hip/hip_runtime.h>
#include <stdint.h>

#define N_NODES 4096
#define K_NN    40
#define B_CLOUDS 8
#define F_IN    8
#define H_DIM   64
#define O_DIM   128

#define OUT_FEAT_ELEMS (B_CLOUDS * N_NODES * O_DIM)   // 4194304
#define EDGES          (B_CLOUDS * N_NODES * K_NN)    // 1310720

typedef short bf16x8 __attribute__((ext_vector_type(8)));
typedef float f32x4  __attribute__((ext_vector_type(4)));

__device__ __forceinline__ unsigned short f2bf(float f) {
    unsigned u = __float_as_uint(f);
    unsigned r = (u + 0x7FFFu + ((u >> 16) & 1u)) >> 16;   // RNE
    return (unsigned short)r;
}

// wave_shr:1 — lane i receives lane i-1's value (COLD fallback path only).
__device__ __forceinline__ unsigned shr1_dpp(unsigned v) {
    return (unsigned)__builtin_amdgcn_update_dpp(0, (int)v, 0x138, 0xF, 0xF, true);
}

// One sorted-insert step (proven v3/v5 machinery) — COLD fallback only.
#define INS_STEP(mask_, dreg_, Rhi_, Rlo_)                                         \
    {                                                                              \
        const int src = (int)__builtin_ctzll(mask_);                               \
        mask_ &= mask_ - 1;                                                        \
        const unsigned long long kb =                                              \
            ((unsigned long long)(unsigned)__builtin_amdgcn_readlane((int)(dreg_), src) << 32) \
            | (unsigned)((c << 6) | src);                                          \
        const unsigned long long RP = ((unsigned long long)Rhi_ << 32) | Rlo_;     \
        const bool keep = (RP <= kb);                                              \
        const unsigned uplo = shr1_dpp(Rlo_);                                      \
        const unsigned uphi = shr1_dpp(Rhi_);                                      \
        const unsigned long long up = ((unsigned long long)uphi << 32) | uplo;     \
        const unsigned long long mx = (up > kb) ? up : kb;                         \
        const unsigned long long nw = keep ? RP : mx;                              \
        Rhi_ = (unsigned)(nw >> 32);                                               \
        Rlo_ = (unsigned)nw;                                                       \
    }

// ---------------------------------------------------------------------------
// Kernel A: exact KNN v10 — v9's branch-free pipeline, TWO targets per wave.
// R6 counters proved the v9 kernel is LDS-PIPE-bound (per-CU DS pipe:
// 128 b128 reads/target dominates; VALU only ~45% of time). Sharing each
// position read across 2 targets halves DS reads/target. Branch-free body
// keeps live state ~40 VGPR (no serial-insert lists — R5's spill cause).
//   P1: dist A+B + 4x top-1 mins each (self d2=0 rides along).
//   RS: 18-bit truncated radix, rank 41, A/B interleaved — proven.
//   P2: recompute + ballot/mbcnt compaction into qual[wave][tgt][64].
//   Sort: two 64-lane bitonic sorts, interleaved for ILP; emit skips self.
//   Overflow (>64 quals, P~3e-6): COLD exact serial-insert fallback.
// ---------------------------------------------------------------------------
__global__ __launch_bounds__(1024, 8) void knn_kernel(const float* __restrict__ pos,
                                                      float* __restrict__ out)
{
    __shared__ float4 ppos[N_NODES];                 // 64 KB
    __shared__ unsigned long long qual[16][2][64];   // 16 KB -> 80 KB total

    const int b  = blockIdx.x >> 7;           // 128 blocks per cloud
    const int i0 = (blockIdx.x & 127) << 5;   // 32 targets per block
    const float* posb = pos + (size_t)b * N_NODES * 3;

    for (int n = threadIdx.x; n < N_NODES; n += 1024) {
        ppos[n] = make_float4(posb[3 * n], posb[3 * n + 1], posb[3 * n + 2], 0.f);
    }
    __syncthreads();

    const int wave = threadIdx.x >> 6;
    const int lane = threadIdx.x & 63;
    const int iA = i0 + (wave << 1);
    const int iB = iA + 1;

    const float4 pa4 = ppos[iA];
    const float4 pb4 = ppos[iB];
    const float pax = pa4.x, pay = pa4.y, paz = pa4.z;
    const float pbx = pb4.x, pby = pb4.y, pbz = pb4.z;

    // ---- pass 1: one LDS sweep feeds BOTH targets; 4x top-1 mins each ----
    unsigned mA0 = ~0u, mA1 = ~0u, mA2 = ~0u, mA3 = ~0u;
    unsigned mB0 = ~0u, mB1 = ~0u, mB2 = ~0u, mB3 = ~0u;
#pragma unroll 8
    for (int c = 0; c < 64; ++c) {
        const float4 p = ppos[(c << 6) | lane];
        // bitwise-exact fp32: ((dx*dx + dy*dy) + dz*dz), no FMA contraction
        const float dxA = __fsub_rn(pax, p.x);
        const float dyA = __fsub_rn(pay, p.y);
        const float dzA = __fsub_rn(paz, p.z);
        const float d2A = __fadd_rn(__fadd_rn(__fmul_rn(dxA, dxA), __fmul_rn(dyA, dyA)),
                                    __fmul_rn(dzA, dzA));
        const float dxB = __fsub_rn(pbx, p.x);
        const float dyB = __fsub_rn(pby, p.y);
        const float dzB = __fsub_rn(pbz, p.z);
        const float d2B = __fadd_rn(__fadd_rn(__fmul_rn(dxB, dxB), __fmul_rn(dyB, dyB)),
                                    __fmul_rn(dzB, dzB));
        const unsigned dA = __float_as_uint(d2A);
        const unsigned dB = __float_as_uint(d2B);
        if ((c & 3) == 0)      { mA0 = min(mA0, dA); mB0 = min(mB0, dB); }
        else if ((c & 3) == 1) { mA1 = min(mA1, dA); mB1 = min(mB1, dB); }
        else if ((c & 3) == 2) { mA2 = min(mA2, dA); mB2 = min(mB2, dB); }
        else                   { mA3 = min(mA3, dA); mB3 = min(mB3, dB); }
    }

    // ---- truncated radix-select (A/B interleaved): t >= 40th real dist ----
    // kept = 256 per-(lane,class) mins incl. one artificial 0 (self); rank-41
    // of kept >= rank-40 of real; 18 bits + round-up => superset threshold.
    unsigned accA = 0, accB = 0;
    for (int bit = 30; bit >= 13; --bit) {
        const unsigned tA = accA | (1u << bit);
        const unsigned tB = accB | (1u << bit);
        const int cA = __popcll(__ballot(mA0 < tA)) + __popcll(__ballot(mA1 < tA))
                     + __popcll(__ballot(mA2 < tA)) + __popcll(__ballot(mA3 < tA));
        const int cB = __popcll(__ballot(mB0 < tB)) + __popcll(__ballot(mB1 < tB))
                     + __popcll(__ballot(mB2 < tB)) + __popcll(__ballot(mB3 < tB));
        if (cA <= K_NN) accA = tA;
        if (cB <= K_NN) accB = tB;
    }
    const unsigned thA = accA | 0x1FFFu;
    const unsigned thB = accB | 0x1FFFu;

    // ---- pass 2: one LDS sweep, branch-free compaction for both targets ----
    unsigned long long* qA = qual[wave][0];
    unsigned long long* qB = qual[wave][1];
    int baseA = 0, baseB = 0;
#pragma unroll 4
    for (int c = 0; c < 64; ++c) {
        const float4 p = ppos[(c << 6) | lane];
        const float dxA = __fsub_rn(pax, p.x);
        const float dyA = __fsub_rn(pay, p.y);
        const float dzA = __fsub_rn(paz, p.z);
        const float d2A = __fadd_rn(__fadd_rn(__fmul_rn(dxA, dxA), __fmul_rn(dyA, dyA)),
                                    __fmul_rn(dzA, dzA));
        const float dxB = __fsub_rn(pbx, p.x);
        const float dyB = __fsub_rn(pby, p.y);
        const float dzB = __fsub_rn(pbz, p.z);
        const float d2B = __fadd_rn(__fadd_rn(__fmul_rn(dxB, dxB), __fmul_rn(dyB, dyB)),
                                    __fmul_rn(dzB, dzB));
        const unsigned dA = __float_as_uint(d2A);
        const unsigned dB = __float_as_uint(d2B);
        const unsigned jj = (unsigned)((c << 6) | lane);

        const bool sA = dA <= thA;
        const unsigned long long mkA = __ballot(sA);
        const unsigned mbA = __builtin_amdgcn_mbcnt_hi(
            (unsigned)(mkA >> 32), __builtin_amdgcn_mbcnt_lo((unsigned)mkA, 0u));
        const int idxA = baseA + (int)mbA;
        if (sA && idxA < 64)
            qA[idxA] = ((unsigned long long)dA << 32) | jj;
        baseA += (int)__popcll(mkA);

        const bool sB = dB <= thB;
        const unsigned long long mkB = __ballot(sB);
        const unsigned mbB = __builtin_amdgcn_mbcnt_hi(
            (unsigned)(mkB >> 32), __builtin_amdgcn_mbcnt_lo((unsigned)mkB, 0u));
        const int idxB = baseB + (int)mbB;
        if (sB && idxB < 64)
            qB[idxB] = ((unsigned long long)dB << 32) | jj;
        baseB += (int)__popcll(mkB);
    }

    float* src_out = out + OUT_FEAT_ELEMS;
    float* tgt_out = src_out + EDGES;
    const int giA = b * N_NODES + iA;
    const int giB = giA + 1;

    if (baseA <= 64 && baseB <= 64) {
        // ---- two interleaved 64-lane bitonic sorts (ILP on shfl chains) ----
        unsigned long long keyA = (lane < baseA) ? qA[lane] : ~0ull;
        unsigned long long keyB = (lane < baseB) ? qB[lane] : ~0ull;
#pragma unroll
        for (int k = 2; k <= 64; k <<= 1) {
#pragma unroll
            for (int j = k >> 1; j > 0; j >>= 1) {
                const unsigned long long prtA = __shfl_xor(keyA, j, 64);
                const unsigned long long prtB = __shfl_xor(keyB, j, 64);
                const bool up = (lane & k) == 0;
                const bool takeMin = (((lane & j) == 0) == up);
                const bool lessA = keyA < prtA;
                const unsigned long long mnA = lessA ? keyA : prtA;
                const unsigned long long mxA = lessA ? prtA : keyA;
                keyA = takeMin ? mnA : mxA;
                const bool lessB = keyB < prtB;
                const unsigned long long mnB = lessB ? keyB : prtB;
                const unsigned long long mxB = lessB ? prtB : keyB;
                keyB = takeMin ? mnB : mxB;
            }
        }
        // locate selves (low word == target id; d2=0 always qualifies), emit
        const unsigned loA = (unsigned)keyA;
        const unsigned loB = (unsigned)keyB;
        const int psA = (int)__builtin_ctzll(__ballot(loA == (unsigned)iA));
        const int psB = (int)__builtin_ctzll(__ballot(loB == (unsigned)iB));
        const int elA = lane - (lane > psA ? 1 : 0);
        const int elB = lane - (lane > psB ? 1 : 0);
        if (lane != psA && elA < K_NN) {
            src_out[(size_t)giA * K_NN + elA] = (float)(b * N_NODES + (int)loA);
            tgt_out[(size_t)giA * K_NN + elA] = (float)giA;
        }
        if (lane != psB && elB < K_NN) {
            src_out[(size_t)giB * K_NN + elB] = (float)(b * N_NODES + (int)loB);
            tgt_out[(size_t)giB * K_NN + elB] = (float)giB;
        }
    } else {
        // ---- COLD exact fallback (P~3e-6): proven serial insert, both ----
        const int ci = iA >> 6;
        const int liA = iA & 63;
        const int liB = iB & 63;
        unsigned RAhi = (lane == 0) ? 0u : 0xFFFFFFFFu;
        unsigned RAlo = (lane == 0) ? 0u : 0xFFFFFFFFu;
        unsigned RBhi = RAhi, RBlo = RAlo;
        for (int c = 0; c < 64; ++c) {
            const float4 p = ppos[(c << 6) | lane];
            const float dxA = __fsub_rn(pax, p.x);
            const float dyA = __fsub_rn(pay, p.y);
            const float dzA = __fsub_rn(paz, p.z);
            const float d2A = __fadd_rn(__fadd_rn(__fmul_rn(dxA, dxA), __fmul_rn(dyA, dyA)),
                                        __fmul_rn(dzA, dzA));
            const float dxB = __fsub_rn(pbx, p.x);
            const float dyB = __fsub_rn(pby, p.y);
            const float dzB = __fsub_rn(pbz, p.z);
            const float d2B = __fadd_rn(__fadd_rn(__fmul_rn(dxB, dxB), __fmul_rn(dyB, dyB)),
                                        __fmul_rn(dzB, dzB));
            const unsigned dA = __float_as_uint(d2A);
            const unsigned dB = __float_as_uint(d2B);
            unsigned long long maskA = __ballot(dA <= thA);
            unsigned long long maskB = __ballot(dB <= thB);
            if (c == ci) {
                maskA &= ~(1ull << liA);
                maskB &= ~(1ull << liB);
            }
            while (maskA) INS_STEP(maskA, dA, RAhi, RAlo);
            while (maskB) INS_STEP(maskB, dB, RBhi, RBlo);
        }
        const unsigned el = (unsigned)(lane - 1);
        if (el < K_NN) {
            src_out[(size_t)giA * K_NN + el] = (float)(b * N_NODES + (int)RAlo);
            tgt_out[(size_t)giA * K_NN + el] = (float)giA;
            src_out[(size_t)giB * K_NN + el] = (float)(b * N_NODES + (int)RBlo);
            tgt_out[(size_t)giB * K_NN + el] = (float)giB;
        }
    }
}

// ---------------------------------------------------------------------------
// Kernel P: precompute W2 and W1 bf16 B-fragments into d_ws — R14, proven.
// ---------------------------------------------------------------------------
__global__ __launch_bounds__(256) void prep_kernel(const float* __restrict__ W2,
                                                   const float* __restrict__ W1,
                                                   unsigned short* __restrict__ ws)
{
    const int idx = blockIdx.x * 256 + threadIdx.x;   // 0..10239
    if (idx < 8192) {
        const int j    = idx & 7;
        const int lane = (idx >> 3) & 63;
        const int kt   = (idx >> 9) & 1;
        const int nt   = idx >> 10;
        const int k = kt * 32 + (lane >> 4) * 8 + j;
        const int n = nt * 16 + (lane & 15);
        ws[idx] = f2bf(W2[k * O_DIM + n]);
    } else if (idx < 8192 + 2048) {
        const int t = idx - 8192;
        const int j    = t & 7;
        const int lane = (t >> 3) & 63;
        const int nt   = t >> 9;          // 0..3
        const int k = (lane >> 4) * 8 + j;          // 0..31
        const int n = nt * 16 + (lane & 15);        // hidden channel
        ws[idx] = (k < 11) ? f2bf(W1[k * H_DIM + n]) : (unsigned short)0;
    }
}

// ---------------------------------------------------------------------------
// Kernel B: per-edge MLP, both layers MFMA — UNCHANGED from R14 (proven).
// ---------------------------------------------------------------------------
#define HSTR 72   // Hh row stride (bf16): 144 B
#define KSTR 40   // msg row stride (bf16): 80 B, 16B-aligned rows

__global__ __launch_bounds__(256, 4) void conv_kernel(
    const float* __restrict__ x, const float* __restrict__ pos,
    const unsigned short* __restrict__ w2f,   // d_ws: w2 frags [0,8192)
    const unsigned short* __restrict__ w1f,   // d_ws: w1 frags [8192,10240)
    const float* __restrict__ b1, const float* __restrict__ b2,
    float* __restrict__ out)
{
    __shared__ __align__(16) unsigned short Hh[4][48 * HSTR];    // 27648 B

    const int b    = blockIdx.x >> 10;
    const int i0   = (blockIdx.x & 1023) << 2;
    const int wave = threadIdx.x >> 6;
    const int lane = threadIdx.x & 63;
    const int quad = lane >> 4;
    const int col  = lane & 15;
    const int i    = i0 + wave;
    const int gi   = b * N_NODES + i;

    unsigned short* Hw = Hh[wave];

    // ---- phase 1: lane n (<48) gathers message row n, stages bf16 to LDS ----
    const float* src_edges = out + OUT_FEAT_ELEMS;
    if (lane < 48) {
        int j;
        if (lane < K_NN) j = (int)src_edges[(size_t)gi * K_NN + lane] - b * N_NODES;
        else             j = i;   // rows 40..47: self row + pad dups (max-safe)
        const float* xr = x + ((size_t)b * N_NODES + j) * F_IN;
        float4 xa = *(const float4*)xr;
        float4 xb = *(const float4*)(xr + 4);
        const float* pj = pos + ((size_t)b * N_NODES + j) * 3;
        const float* pi = pos + ((size_t)b * N_NODES + i) * 3;
        unsigned w[16];
#pragma unroll
        for (int t = 0; t < 16; ++t) w[t] = 0;
        w[0] = (unsigned)f2bf(xa.x) | ((unsigned)f2bf(xa.y) << 16);
        w[1] = (unsigned)f2bf(xa.z) | ((unsigned)f2bf(xa.w) << 16);
        w[2] = (unsigned)f2bf(xb.x) | ((unsigned)f2bf(xb.y) << 16);
        w[3] = (unsigned)f2bf(xb.z) | ((unsigned)f2bf(xb.w) << 16);
        w[4] = (unsigned)f2bf(pj[0] - pi[0]) | ((unsigned)f2bf(pj[1] - pi[1]) << 16);
        w[5] = (unsigned)f2bf(pj[2] - pi[2]);
        unsigned* mrow = (unsigned*)(Hw + lane * KSTR);
        *(uint4*)(mrow)      = make_uint4(w[0], w[1], w[2], w[3]);
        *(uint4*)(mrow + 4)  = make_uint4(w[4], w[5], w[6], w[7]);
        *(uint4*)(mrow + 8)  = make_uint4(w[8], w[9], w[10], w[11]);
        *(uint4*)(mrow + 12) = make_uint4(w[12], w[13], w[14], w[15]);
    }
    // same-wave ds_write -> ds_read: ordered by lgkmcnt, no barrier needed

    // ---- layer 1 via MFMA: H[48x64] = msg[48x32] . W1[32x64] ----
    bf16x8 Am[3];
#pragma unroll
    for (int mt = 0; mt < 3; ++mt)
        Am[mt] = *(const bf16x8*)&Hw[(mt * 16 + col) * KSTR + quad * 8];

    const bf16x8* W1f = (const bf16x8*)w1f;
    float hreg[12][4];
#pragma unroll
    for (int nt = 0; nt < 4; ++nt) {
        bf16x8 Bn = W1f[nt * 64 + lane];
        const float bias = b1[nt * 16 + col];
        f32x4 d0 = {bias, bias, bias, bias};
        f32x4 d1 = d0, d2 = d0;
        d0 = __builtin_amdgcn_mfma_f32_16x16x32_bf16(Am[0], Bn, d0, 0, 0, 0);
        d1 = __builtin_amdgcn_mfma_f32_16x16x32_bf16(Am[1], Bn, d1, 0, 0, 0);
        d2 = __builtin_amdgcn_mfma_f32_16x16x32_bf16(Am[2], Bn, d2, 0, 0, 0);
#pragma unroll
        for (int r = 0; r < 4; ++r) {
            hreg[nt * 3 + 0][r] = fmaxf(d0[r], 0.0f);
            hreg[nt * 3 + 1][r] = fmaxf(d1[r], 0.0f);
            hreg[nt * 3 + 2][r] = fmaxf(d2[r], 0.0f);
        }
    }

    // msg fully consumed -> overwrite region as Hh[row][hidden]
#pragma unroll
    for (int nt = 0; nt < 4; ++nt)
#pragma unroll
        for (int mt = 0; mt < 3; ++mt)
#pragma unroll
            for (int r = 0; r < 4; ++r)
                Hw[(mt * 16 + quad * 4 + r) * HSTR + nt * 16 + col] =
                    f2bf(hreg[nt * 3 + mt][r]);

    // ---- layer 2 via MFMA ----
    bf16x8 Af[3][2];
#pragma unroll
    for (int mt = 0; mt < 3; ++mt)
#pragma unroll
        for (int kt = 0; kt < 2; ++kt)
            Af[mt][kt] = *(const bf16x8*)&Hw[(mt * 16 + col) * HSTR + kt * 32 + quad * 8];

    const bf16x8* Bws = (const bf16x8*)w2f;
#pragma unroll
    for (int nt = 0; nt < 8; ++nt) {
        bf16x8 B0 = Bws[nt * 128 + lane];
        bf16x8 B1 = Bws[nt * 128 + 64 + lane];

        f32x4 c0 = {0.f, 0.f, 0.f, 0.f};
        f32x4 c1 = {0.f, 0.f, 0.f, 0.f};
        f32x4 c2 = {0.f, 0.f, 0.f, 0.f};
        c0 = __builtin_amdgcn_mfma_f32_16x16x32_bf16(Af[0][0], B0, c0, 0, 0, 0);
        c1 = __builtin_amdgcn_mfma_f32_16x16x32_bf16(Af[1][0], B0, c1, 0, 0, 0);
        c2 = __builtin_amdgcn_mfma_f32_16x16x32_bf16(Af[2][0], B0, c2, 0, 0, 0);
        c0 = __builtin_amdgcn_mfma_f32_16x16x32_bf16(Af[0][1], B1, c0, 0, 0, 0);
        c1 = __builtin_amdgcn_mfma_f32_16x16x32_bf16(Af[1][1], B1, c1, 0, 0, 0);
        c2 = __builtin_amdgcn_mfma_f32_16x16x32_bf16(Af[2][1], B1, c2, 0, 0, 0);

        float vm = c0[0];
        vm = fmaxf(vm, c0[1]); vm = fmaxf(vm, c0[2]); vm = fmaxf(vm, c0[3]);
        vm = fmaxf(vm, c1[0]); vm = fmaxf(vm, c1[1]); vm = fmaxf(vm, c1[2]); vm = fmaxf(vm, c1[3]);
        vm = fmaxf(vm, c2[0]); vm = fmaxf(vm, c2[1]); vm = fmaxf(vm, c2[2]); vm = fmaxf(vm, c2[3]);
        vm = fmaxf(vm, __shfl_xor(vm, 16));
        vm = fmaxf(vm, __shfl_xor(vm, 32));
        vm += b2[nt * 16 + col];

        if (lane < 16) out[(size_t)gi * O_DIM + nt * 16 + lane] = vm;
    }
}

// ---------------------------------------------------------------------------
extern "C" void kernel_launch(void* const* d_in, const int* in_sizes, int n_in,
                              void* d_out, int out_size, void* d_ws, size_t ws_size,
                              hipStream_t stream) {
    const float* x   = (const float*)d_in[0];
    const float* pos = (const float*)d_in[1];
    const float* W1  = (const float*)d_in[2];
    const float* b1  = (const float*)d_in[3];
    const float* W2  = (const float*)d_in[4];
    const float* b2  = (const float*)d_in[5];
    float* out = (float*)d_out;
    unsigned short* ws = (unsigned short*)d_ws;   // 10240 bf16 = 20.5 KB

    prep_kernel<<<40, 256, 0, stream>>>(W2, W1, ws);
    knn_kernel<<<(B_CLOUDS * N_NODES) / 32, 1024, 0, stream>>>(pos, out);
    conv_kernel<<<(B_CLOUDS * N_NODES) / 4, 256, 0, stream>>>(
        x, pos, ws, ws + 8192, b1, b2, out);
}

// Round 8
// 188.831 us; speedup vs baseline: 1.4042x; 1.0401x over previous
//
#include <hip/hip_runtime.h>
#include <stdint.h>

#define N_NODES 4096
#define K_NN    40
#define B_CLOUDS 8
#define F_IN    8
#define H_DIM   64
#define O_DIM   128

#define OUT_FEAT_ELEMS (B_CLOUDS * N_NODES * O_DIM)   // 4194304
#define EDGES          (B_CLOUDS * N_NODES * K_NN)    // 1310720

typedef short bf16x8 __attribute__((ext_vector_type(8)));
typedef float f32x4  __attribute__((ext_vector_type(4)));

__device__ __forceinline__ unsigned short f2bf(float f) {
    unsigned u = __float_as_uint(f);
    unsigned r = (u + 0x7FFFu + ((u >> 16) & 1u)) >> 16;   // RNE
    return (unsigned short)r;
}

// wave_shr:1 — lane i receives lane i-1's value (COLD fallback path only).
__device__ __forceinline__ unsigned shr1_dpp(unsigned v) {
    return (unsigned)__builtin_amdgcn_update_dpp(0, (int)v, 0x138, 0xF, 0xF, true);
}

// One sorted-insert step (proven v3/v5 machinery) — COLD fallback only.
#define INS_STEP(mask_, dreg_, Rhi_, Rlo_)                                         \
    {                                                                              \
        const int src = (int)__builtin_ctzll(mask_);                               \
        mask_ &= mask_ - 1;                                                        \
        const unsigned long long kb =                                              \
            ((unsigned long long)(unsigned)__builtin_amdgcn_readlane((int)(dreg_), src) << 32) \
            | (unsigned)((c << 6) | src);                                          \
        const unsigned long long RP = ((unsigned long long)Rhi_ << 32) | Rlo_;     \
        const bool keep = (RP <= kb);                                              \
        const unsigned uplo = shr1_dpp(Rlo_);                                      \
        const unsigned uphi = shr1_dpp(Rhi_);                                      \
        const unsigned long long up = ((unsigned long long)uphi << 32) | uplo;     \
        const unsigned long long mx = (up > kb) ? up : kb;                         \
        const unsigned long long nw = keep ? RP : mx;                              \
        Rhi_ = (unsigned)(nw >> 32);                                               \
        Rlo_ = (unsigned)nw;                                                       \
    }

// Cheap wave-XOR shuffles for the bitonic stages (avoid ds_bpermute):
#define DPPX1(v)  ((unsigned)__builtin_amdgcn_update_dpp(0, (int)(v), 0xB1, 0xF, 0xF, true)) // quad_perm xor1
#define DPPX2(v)  ((unsigned)__builtin_amdgcn_update_dpp(0, (int)(v), 0x4E, 0xF, 0xF, true)) // quad_perm xor2
#define SWZ4(v)   ((unsigned)__builtin_amdgcn_ds_swizzle((int)(v), 0x101F))                  // xor4
#define SWZ8(v)   ((unsigned)__builtin_amdgcn_ds_swizzle((int)(v), 0x201F))                  // xor8
#define SWZ16(v)  ((unsigned)__builtin_amdgcn_ds_swizzle((int)(v), 0x401F))                  // xor16
#define SX32(v)   ((unsigned)__shfl_xor((int)(v), 32, 64))                                   // xor32

// One bitonic compare-exchange stage on u64 keyA/keyB (A/B interleaved, ILP).
#define CE(K, J, SH)                                                         \
    {                                                                        \
        const unsigned pAl = SH((unsigned)keyA);                             \
        const unsigned pAh = SH((unsigned)(keyA >> 32));                     \
        const unsigned pBl = SH((unsigned)keyB);                             \
        const unsigned pBh = SH((unsigned)(keyB >> 32));                     \
        const unsigned long long pA = ((unsigned long long)pAh << 32) | pAl; \
        const unsigned long long pB = ((unsigned long long)pBh << 32) | pBl; \
        const bool up = (lane & (K)) == 0;                                   \
        const bool tk = ((lane & (J)) == 0) == up;                           \
        const bool lA = keyA < pA;                                           \
        const unsigned long long mnA = lA ? keyA : pA;                       \
        const unsigned long long mxA = lA ? pA : keyA;                       \
        keyA = tk ? mnA : mxA;                                               \
        const bool lB = keyB < pB;                                           \
        const unsigned long long mnB = lB ? keyB : pB;                       \
        const unsigned long long mxB = lB ? pB : keyB;                       \
        keyB = tk ? mnB : mxB;                                               \
    }

// ---------------------------------------------------------------------------
// Kernel A: exact KNN v11 — v10 + block-prune P2 + DS-light bitonic.
//   P1 TRANSPOSED: lane l scans its own block [l*64, l*64+64) via XOR-stagger
//       addr (l<<6)|(c^l) (index%8 distribution == coalesced, conflict-free).
//       Per-(block, offset&3) mins -> same 256-kept threshold quality; block
//       min lives in lane l's regs for free.
//   RS: 18-bit truncated radix, rank 41 — proven.
//   PRUNE: skipmask = ballot(bminA<=thA) | ballot(bminB<=thB); P2 visits only
//       chunks with >=1 qualifier (~49 of 64 expected). Self block always set.
//   P2: coalesced recompute + ballot/mbcnt compaction (proven).
//   Sort: bitonic with DPP(j=1,2) / ds_swizzle(j=4,8,16) / shfl(j=32):
//       DS ops 84 -> 20 per wave.
//   Overflow (>64 quals, P~3e-6): COLD exact serial-insert over all chunks.
// ---------------------------------------------------------------------------
__global__ __launch_bounds__(1024, 8) void knn_kernel(const float* __restrict__ pos,
                                                      float* __restrict__ out)
{
    __shared__ float4 ppos[N_NODES];                 // 64 KB
    __shared__ unsigned long long qual[16][2][64];   // 16 KB -> 80 KB total

    const int b  = blockIdx.x >> 7;           // 128 blocks per cloud
    const int i0 = (blockIdx.x & 127) << 5;   // 32 targets per block
    const float* posb = pos + (size_t)b * N_NODES * 3;

    for (int n = threadIdx.x; n < N_NODES; n += 1024) {
        ppos[n] = make_float4(posb[3 * n], posb[3 * n + 1], posb[3 * n + 2], 0.f);
    }
    __syncthreads();

    const int wave = threadIdx.x >> 6;
    const int lane = threadIdx.x & 63;
    const int iA = i0 + (wave << 1);
    const int iB = iA + 1;

    const float4 pa4 = ppos[iA];
    const float4 pb4 = ppos[iB];
    const float pax = pa4.x, pay = pa4.y, paz = pa4.z;
    const float pbx = pb4.x, pby = pb4.y, pbz = pb4.z;

    // ---- pass 1 (transposed): lane l covers block l; 4 class-mins each ----
    unsigned mA0 = ~0u, mA1 = ~0u, mA2 = ~0u, mA3 = ~0u;
    unsigned mB0 = ~0u, mB1 = ~0u, mB2 = ~0u, mB3 = ~0u;
#pragma unroll 8
    for (int c = 0; c < 64; ++c) {
        const int jj = (lane << 6) | (c ^ lane);   // block l, XOR-staggered
        const float4 p = ppos[jj];
        // bitwise-exact fp32: ((dx*dx + dy*dy) + dz*dz), no FMA contraction
        const float dxA = __fsub_rn(pax, p.x);
        const float dyA = __fsub_rn(pay, p.y);
        const float dzA = __fsub_rn(paz, p.z);
        const float d2A = __fadd_rn(__fadd_rn(__fmul_rn(dxA, dxA), __fmul_rn(dyA, dyA)),
                                    __fmul_rn(dzA, dzA));
        const float dxB = __fsub_rn(pbx, p.x);
        const float dyB = __fsub_rn(pby, p.y);
        const float dzB = __fsub_rn(pbz, p.z);
        const float d2B = __fadd_rn(__fadd_rn(__fmul_rn(dxB, dxB), __fmul_rn(dyB, dyB)),
                                    __fmul_rn(dzB, dzB));
        const unsigned dA = __float_as_uint(d2A);
        const unsigned dB = __float_as_uint(d2B);
        // class = c&3 (wave-uniform). Per-lane it partitions the block by
        // offset&3 ^ (l&3): same 256-value kept set, permuted across regs.
        if ((c & 3) == 0)      { mA0 = min(mA0, dA); mB0 = min(mB0, dB); }
        else if ((c & 3) == 1) { mA1 = min(mA1, dA); mB1 = min(mB1, dB); }
        else if ((c & 3) == 2) { mA2 = min(mA2, dA); mB2 = min(mB2, dB); }
        else                   { mA3 = min(mA3, dA); mB3 = min(mB3, dB); }
    }

    // ---- truncated radix-select (A/B interleaved): t >= 40th real dist ----
    unsigned accA = 0, accB = 0;
    for (int bit = 30; bit >= 13; --bit) {
        const unsigned tA = accA | (1u << bit);
        const unsigned tB = accB | (1u << bit);
        const int cA = __popcll(__ballot(mA0 < tA)) + __popcll(__ballot(mA1 < tA))
                     + __popcll(__ballot(mA2 < tA)) + __popcll(__ballot(mA3 < tA));
        const int cB = __popcll(__ballot(mB0 < tB)) + __popcll(__ballot(mB1 < tB))
                     + __popcll(__ballot(mB2 < tB)) + __popcll(__ballot(mB3 < tB));
        if (cA <= K_NN) accA = tA;
        if (cB <= K_NN) accB = tB;
    }
    const unsigned thA = accA | 0x1FFFu;
    const unsigned thB = accB | 0x1FFFu;

    // ---- prune mask: bit l set iff block l holds a qualifier for A or B ----
    const unsigned bmA = min(min(mA0, mA1), min(mA2, mA3));
    const unsigned bmB = min(min(mB0, mB1), min(mB2, mB3));
    unsigned long long sm = __ballot(bmA <= thA) | __ballot(bmB <= thB);
    // self blocks always set (d2=0 <= th), so emit logic below is safe.

    // ---- pass 2: visit only qualifying chunks; branch-free compaction ----
    unsigned long long* qA = qual[wave][0];
    unsigned long long* qB = qual[wave][1];
    int baseA = 0, baseB = 0;
    while (sm) {
        const int c = (int)__builtin_ctzll(sm);
        sm &= sm - 1;
        const float4 p = ppos[(c << 6) | lane];
        const float dxA = __fsub_rn(pax, p.x);
        const float dyA = __fsub_rn(pay, p.y);
        const float dzA = __fsub_rn(paz, p.z);
        const float d2A = __fadd_rn(__fadd_rn(__fmul_rn(dxA, dxA), __fmul_rn(dyA, dyA)),
                                    __fmul_rn(dzA, dzA));
        const float dxB = __fsub_rn(pbx, p.x);
        const float dyB = __fsub_rn(pby, p.y);
        const float dzB = __fsub_rn(pbz, p.z);
        const float d2B = __fadd_rn(__fadd_rn(__fmul_rn(dxB, dxB), __fmul_rn(dyB, dyB)),
                                    __fmul_rn(dzB, dzB));
        const unsigned dA = __float_as_uint(d2A);
        const unsigned dB = __float_as_uint(d2B);
        const unsigned jj = (unsigned)((c << 6) | lane);

        const bool sA = dA <= thA;
        const unsigned long long mkA = __ballot(sA);
        const unsigned mbA = __builtin_amdgcn_mbcnt_hi(
            (unsigned)(mkA >> 32), __builtin_amdgcn_mbcnt_lo((unsigned)mkA, 0u));
        const int idxA = baseA + (int)mbA;
        if (sA && idxA < 64)
            qA[idxA] = ((unsigned long long)dA << 32) | jj;
        baseA += (int)__popcll(mkA);

        const bool sB = dB <= thB;
        const unsigned long long mkB = __ballot(sB);
        const unsigned mbB = __builtin_amdgcn_mbcnt_hi(
            (unsigned)(mkB >> 32), __builtin_amdgcn_mbcnt_lo((unsigned)mkB, 0u));
        const int idxB = baseB + (int)mbB;
        if (sB && idxB < 64)
            qB[idxB] = ((unsigned long long)dB << 32) | jj;
        baseB += (int)__popcll(mkB);
    }

    float* src_out = out + OUT_FEAT_ELEMS;
    float* tgt_out = src_out + EDGES;
    const int giA = b * N_NODES + iA;
    const int giB = giA + 1;

    if (baseA <= 64 && baseB <= 64) {
        // ---- interleaved bitonic, DS-light shuffles (21 stages) ----
        unsigned long long keyA = (lane < baseA) ? qA[lane] : ~0ull;
        unsigned long long keyB = (lane < baseB) ? qB[lane] : ~0ull;
        CE(2, 1, DPPX1)
        CE(4, 2, DPPX2)  CE(4, 1, DPPX1)
        CE(8, 4, SWZ4)   CE(8, 2, DPPX2)  CE(8, 1, DPPX1)
        CE(16, 8, SWZ8)  CE(16, 4, SWZ4)  CE(16, 2, DPPX2) CE(16, 1, DPPX1)
        CE(32, 16, SWZ16) CE(32, 8, SWZ8) CE(32, 4, SWZ4)  CE(32, 2, DPPX2) CE(32, 1, DPPX1)
        CE(64, 32, SX32) CE(64, 16, SWZ16) CE(64, 8, SWZ8) CE(64, 4, SWZ4)  CE(64, 2, DPPX2) CE(64, 1, DPPX1)
        // locate selves (low word == target id; d2=0 always qualifies), emit
        const unsigned loA = (unsigned)keyA;
        const unsigned loB = (unsigned)keyB;
        const int psA = (int)__builtin_ctzll(__ballot(loA == (unsigned)iA));
        const int psB = (int)__builtin_ctzll(__ballot(loB == (unsigned)iB));
        const int elA = lane - (lane > psA ? 1 : 0);
        const int elB = lane - (lane > psB ? 1 : 0);
        if (lane != psA && elA < K_NN) {
            src_out[(size_t)giA * K_NN + elA] = (float)(b * N_NODES + (int)loA);
            tgt_out[(size_t)giA * K_NN + elA] = (float)giA;
        }
        if (lane != psB && elB < K_NN) {
            src_out[(size_t)giB * K_NN + elB] = (float)(b * N_NODES + (int)loB);
            tgt_out[(size_t)giB * K_NN + elB] = (float)giB;
        }
    } else {
        // ---- COLD exact fallback (P~3e-6): full sweep, serial insert ----
        const int ci = iA >> 6;
        const int liA = iA & 63;
        const int liB = iB & 63;
        unsigned RAhi = (lane == 0) ? 0u : 0xFFFFFFFFu;
        unsigned RAlo = (lane == 0) ? 0u : 0xFFFFFFFFu;
        unsigned RBhi = RAhi, RBlo = RAlo;
        for (int c = 0; c < 64; ++c) {
            const float4 p = ppos[(c << 6) | lane];
            const float dxA = __fsub_rn(pax, p.x);
            const float dyA = __fsub_rn(pay, p.y);
            const float dzA = __fsub_rn(paz, p.z);
            const float d2A = __fadd_rn(__fadd_rn(__fmul_rn(dxA, dxA), __fmul_rn(dyA, dyA)),
                                        __fmul_rn(dzA, dzA));
            const float dxB = __fsub_rn(pbx, p.x);
            const float dyB = __fsub_rn(pby, p.y);
            const float dzB = __fsub_rn(pbz, p.z);
            const float d2B = __fadd_rn(__fadd_rn(__fmul_rn(dxB, dxB), __fmul_rn(dyB, dyB)),
                                        __fmul_rn(dzB, dzB));
            const unsigned dA = __float_as_uint(d2A);
            const unsigned dB = __float_as_uint(d2B);
            unsigned long long maskA = __ballot(dA <= thA);
            unsigned long long maskB = __ballot(dB <= thB);
            if (c == ci) {
                maskA &= ~(1ull << liA);
                maskB &= ~(1ull << liB);
            }
            while (maskA) INS_STEP(maskA, dA, RAhi, RAlo);
            while (maskB) INS_STEP(maskB, dB, RBhi, RBlo);
        }
        const unsigned el = (unsigned)(lane - 1);
        if (el < K_NN) {
            src_out[(size_t)giA * K_NN + el] = (float)(b * N_NODES + (int)RAlo);
            tgt_out[(size_t)giA * K_NN + el] = (float)giA;
            src_out[(size_t)giB * K_NN + el] = (float)(b * N_NODES + (int)RBlo);
            tgt_out[(size_t)giB * K_NN + el] = (float)giB;
        }
    }
}

// ---------------------------------------------------------------------------
// Kernel P: precompute W2 and W1 bf16 B-fragments into d_ws — R14, proven.
// ---------------------------------------------------------------------------
__global__ __launch_bounds__(256) void prep_kernel(const float* __restrict__ W2,
                                                   const float* __restrict__ W1,
                                                   unsigned short* __restrict__ ws)
{
    const int idx = blockIdx.x * 256 + threadIdx.x;   // 0..10239
    if (idx < 8192) {
        const int j    = idx & 7;
        const int lane = (idx >> 3) & 63;
        const int kt   = (idx >> 9) & 1;
        const int nt   = idx >> 10;
        const int k = kt * 32 + (lane >> 4) * 8 + j;
        const int n = nt * 16 + (lane & 15);
        ws[idx] = f2bf(W2[k * O_DIM + n]);
    } else if (idx < 8192 + 2048) {
        const int t = idx - 8192;
        const int j    = t & 7;
        const int lane = (t >> 3) & 63;
        const int nt   = t >> 9;          // 0..3
        const int k = (lane >> 4) * 8 + j;          // 0..31
        const int n = nt * 16 + (lane & 15);        // hidden channel
        ws[idx] = (k < 11) ? f2bf(W1[k * H_DIM + n]) : (unsigned short)0;
    }
}

// ---------------------------------------------------------------------------
// Kernel B: per-edge MLP, both layers MFMA — UNCHANGED from R14 (proven).
// ---------------------------------------------------------------------------
#define HSTR 72   // Hh row stride (bf16): 144 B
#define KSTR 40   // msg row stride (bf16): 80 B, 16B-aligned rows

__global__ __launch_bounds__(256, 4) void conv_kernel(
    const float* __restrict__ x, const float* __restrict__ pos,
    const unsigned short* __restrict__ w2f,   // d_ws: w2 frags [0,8192)
    const unsigned short* __restrict__ w1f,   // d_ws: w1 frags [8192,10240)
    const float* __restrict__ b1, const float* __restrict__ b2,
    float* __restrict__ out)
{
    __shared__ __align__(16) unsigned short Hh[4][48 * HSTR];    // 27648 B

    const int b    = blockIdx.x >> 10;
    const int i0   = (blockIdx.x & 1023) << 2;
    const int wave = threadIdx.x >> 6;
    const int lane = threadIdx.x & 63;
    const int quad = lane >> 4;
    const int col  = lane & 15;
    const int i    = i0 + wave;
    const int gi   = b * N_NODES + i;

    unsigned short* Hw = Hh[wave];

    // ---- phase 1: lane n (<48) gathers message row n, stages bf16 to LDS ----
    const float* src_edges = out + OUT_FEAT_ELEMS;
    if (lane < 48) {
        int j;
        if (lane < K_NN) j = (int)src_edges[(size_t)gi * K_NN + lane] - b * N_NODES;
        else             j = i;   // rows 40..47: self row + pad dups (max-safe)
        const float* xr = x + ((size_t)b * N_NODES + j) * F_IN;
        float4 xa = *(const float4*)xr;
        float4 xb = *(const float4*)(xr + 4);
        const float* pj = pos + ((size_t)b * N_NODES + j) * 3;
        const float* pi = pos + ((size_t)b * N_NODES + i) * 3;
        unsigned w[16];
#pragma unroll
        for (int t = 0; t < 16; ++t) w[t] = 0;
        w[0] = (unsigned)f2bf(xa.x) | ((unsigned)f2bf(xa.y) << 16);
        w[1] = (unsigned)f2bf(xa.z) | ((unsigned)f2bf(xa.w) << 16);
        w[2] = (unsigned)f2bf(xb.x) | ((unsigned)f2bf(xb.y) << 16);
        w[3] = (unsigned)f2bf(xb.z) | ((unsigned)f2bf(xb.w) << 16);
        w[4] = (unsigned)f2bf(pj[0] - pi[0]) | ((unsigned)f2bf(pj[1] - pi[1]) << 16);
        w[5] = (unsigned)f2bf(pj[2] - pi[2]);
        unsigned* mrow = (unsigned*)(Hw + lane * KSTR);
        *(uint4*)(mrow)      = make_uint4(w[0], w[1], w[2], w[3]);
        *(uint4*)(mrow + 4)  = make_uint4(w[4], w[5], w[6], w[7]);
        *(uint4*)(mrow + 8)  = make_uint4(w[8], w[9], w[10], w[11]);
        *(uint4*)(mrow + 12) = make_uint4(w[12], w[13], w[14], w[15]);
    }
    // same-wave ds_write -> ds_read: ordered by lgkmcnt, no barrier needed

    // ---- layer 1 via MFMA: H[48x64] = msg[48x32] . W1[32x64] ----
    bf16x8 Am[3];
#pragma unroll
    for (int mt = 0; mt < 3; ++mt)
        Am[mt] = *(const bf16x8*)&Hw[(mt * 16 + col) * KSTR + quad * 8];

    const bf16x8* W1f = (const bf16x8*)w1f;
    float hreg[12][4];
#pragma unroll
    for (int nt = 0; nt < 4; ++nt) {
        bf16x8 Bn = W1f[nt * 64 + lane];
        const float bias = b1[nt * 16 + col];
        f32x4 d0 = {bias, bias, bias, bias};
        f32x4 d1 = d0, d2 = d0;
        d0 = __builtin_amdgcn_mfma_f32_16x16x32_bf16(Am[0], Bn, d0, 0, 0, 0);
        d1 = __builtin_amdgcn_mfma_f32_16x16x32_bf16(Am[1], Bn, d1, 0, 0, 0);
        d2 = __builtin_amdgcn_mfma_f32_16x16x32_bf16(Am[2], Bn, d2, 0, 0, 0);
#pragma unroll
        for (int r = 0; r < 4; ++r) {
            hreg[nt * 3 + 0][r] = fmaxf(d0[r], 0.0f);
            hreg[nt * 3 + 1][r] = fmaxf(d1[r], 0.0f);
            hreg[nt * 3 + 2][r] = fmaxf(d2[r], 0.0f);
        }
    }

    // msg fully consumed -> overwrite region as Hh[row][hidden]
#pragma unroll
    for (int nt = 0; nt < 4; ++nt)
#pragma unroll
        for (int mt = 0; mt < 3; ++mt)
#pragma unroll
            for (int r = 0; r < 4; ++r)
                Hw[(mt * 16 + quad * 4 + r) * HSTR + nt * 16 + col] =
                    f2bf(hreg[nt * 3 + mt][r]);

    // ---- layer 2 via MFMA ----
    bf16x8 Af[3][2];
#pragma unroll
    for (int mt = 0; mt < 3; ++mt)
#pragma unroll
        for (int kt = 0; kt < 2; ++kt)
            Af[mt][kt] = *(const bf16x8*)&Hw[(mt * 16 + col) * HSTR + kt * 32 + quad * 8];

    const bf16x8* Bws = (const bf16x8*)w2f;
#pragma unroll
    for (int nt = 0; nt < 8; ++nt) {
        bf16x8 B0 = Bws[nt * 128 + lane];
        bf16x8 B1 = Bws[nt * 128 + 64 + lane];

        f32x4 c0 = {0.f, 0.f, 0.f, 0.f};
        f32x4 c1 = {0.f, 0.f, 0.f, 0.f};
        f32x4 c2 = {0.f, 0.f, 0.f, 0.f};
        c0 = __builtin_amdgcn_mfma_f32_16x16x32_bf16(Af[0][0], B0, c0, 0, 0, 0);
        c1 = __builtin_amdgcn_mfma_f32_16x16x32_bf16(Af[1][0], B0, c1, 0, 0, 0);
        c2 = __builtin_amdgcn_mfma_f32_16x16x32_bf16(Af[2][0], B0, c2, 0, 0, 0);
        c0 = __builtin_amdgcn_mfma_f32_16x16x32_bf16(Af[0][1], B1, c0, 0, 0, 0);
        c1 = __builtin_amdgcn_mfma_f32_16x16x32_bf16(Af[1][1], B1, c1, 0, 0, 0);
        c2 = __builtin_amdgcn_mfma_f32_16x16x32_bf16(Af[2][1], B1, c2, 0, 0, 0);

        float vm = c0[0];
        vm = fmaxf(vm, c0[1]); vm = fmaxf(vm, c0[2]); vm = fmaxf(vm, c0[3]);
        vm = fmaxf(vm, c1[0]); vm = fmaxf(vm, c1[1]); vm = fmaxf(vm, c1[2]); vm = fmaxf(vm, c1[3]);
        vm = fmaxf(vm, c2[0]); vm = fmaxf(vm, c2[1]); vm = fmaxf(vm, c2[2]); vm = fmaxf(vm, c2[3]);
        vm = fmaxf(vm, __shfl_xor(vm, 16));
        vm = fmaxf(vm, __shfl_xor(vm, 32));
        vm += b2[nt * 16 + col];

        if (lane < 16) out[(size_t)gi * O_DIM + nt * 16 + lane] = vm;
    }
}

// ---------------------------------------------------------------------------
extern "C" void kernel_launch(void* const* d_in, const int* in_sizes, int n_in,
                              void* d_out, int out_size, void* d_ws, size_t ws_size,
                              hipStream_t stream) {
    const float* x   = (const float*)d_in[0];
    const float* pos = (const float*)d_in[1];
    const float* W1  = (const float*)d_in[2];
    const float* b1  = (const float*)d_in[3];
    const float* W2  = (const float*)d_in[4];
    const float* b2  = (const float*)d_in[5];
    float* out = (float*)d_out;
    unsigned short* ws = (unsigned short*)d_ws;   // 10240 bf16 = 20.5 KB

    prep_kernel<<<40, 256, 0, stream>>>(W2, W1, ws);
    knn_kernel<<<(B_CLOUDS * N_NODES) / 32, 1024, 0, stream>>>(pos, out);
    conv_kernel<<<(B_CLOUDS * N_NODES) / 4, 256, 0, stream>>>(
        x, pos, ws, ws + 8192, b1, b2, out);
}